// Round 1
// baseline (434.597 us; speedup 1.0000x reference)
//
#include <hip/hip_runtime.h>

// B=4096 rows, N=16384 neurons, F=16384 features.
// One block per row; row staged in LDS (64 KB = exactly the static limit,
// 2 blocks/CU); specialized values held in registers between the mean
// reduction and the rectified store, so HBM traffic = 1x read enc + 1x write.

constexpr int B_ROWS  = 4096;
constexpr int N_NEUR  = 16384;
constexpr int F_FEAT  = 16384;
constexpr int THREADS = 512;
constexpr int VPT     = N_NEUR / THREADS;  // 32 values per thread
constexpr int CHUNK   = 4;                 // float4 granularity
constexpr int ITERS   = VPT / CHUNK;       // 8
constexpr float MEAN_SUB = 0.1f;

__global__ void __launch_bounds__(THREADS, 4)
sensory_kernel(const float* __restrict__ enc,
               const float* __restrict__ w,
               const int*   __restrict__ pref,
               float*       __restrict__ out) {
    __shared__ float row[F_FEAT];  // 64 KB; reused for the reduction later

    const int tid = threadIdx.x;
    const int b   = blockIdx.x;

    // ---- stage encoded_features[b, :] into LDS (coalesced float4) ----
    const float4* __restrict__ rowg4 = (const float4*)(enc + (size_t)b * F_FEAT);
    float4* row4 = (float4*)row;
    #pragma unroll
    for (int j = 0; j < F_FEAT / 4 / THREADS; ++j) {   // 8 iters
        row4[tid + j * THREADS] = rowg4[tid + j * THREADS];
    }
    __syncthreads();

    // ---- pass 1: gather * weight, keep in registers, accumulate sum ----
    float v[VPT];
    float lsum = 0.0f;
    #pragma unroll
    for (int k = 0; k < ITERS; ++k) {
        const int n = k * (THREADS * CHUNK) + tid * CHUNK;
        const int4   p4 = *(const int4*)(pref + n);
        const float4 w4 = *(const float4*)(w + n);
        const float a0 = row[p4.x & (F_FEAT - 1)] * w4.x;
        const float a1 = row[p4.y & (F_FEAT - 1)] * w4.y;
        const float a2 = row[p4.z & (F_FEAT - 1)] * w4.z;
        const float a3 = row[p4.w & (F_FEAT - 1)] * w4.w;
        v[k * 4 + 0] = a0;
        v[k * 4 + 1] = a1;
        v[k * 4 + 2] = a2;
        v[k * 4 + 3] = a3;
        lsum += (a0 + a1) + (a2 + a3);
    }

    // ---- block reduction: wave shuffle, then LDS (reuse row[]) ----
    #pragma unroll
    for (int off = 32; off > 0; off >>= 1)
        lsum += __shfl_down(lsum, off, 64);

    __syncthreads();               // everyone done gathering from row[]
    if ((tid & 63) == 0) row[tid >> 6] = lsum;   // 8 wave partials
    __syncthreads();
    if (tid == 0) {
        float t = 0.0f;
        #pragma unroll
        for (int i = 0; i < THREADS / 64; ++i) t += row[i];
        row[0] = t * (MEAN_SUB / (float)N_NEUR);  // 0.1 * mean
    }
    __syncthreads();
    const float sub = row[0];

    // ---- pass 2: subtract, rectify, coalesced float4 store ----
    float* __restrict__ outrow = out + (size_t)b * N_NEUR;
    #pragma unroll
    for (int k = 0; k < ITERS; ++k) {
        const int n = k * (THREADS * CHUNK) + tid * CHUNK;
        float4 o;
        o.x = fmaxf(v[k * 4 + 0] - sub, 0.0f);
        o.y = fmaxf(v[k * 4 + 1] - sub, 0.0f);
        o.z = fmaxf(v[k * 4 + 2] - sub, 0.0f);
        o.w = fmaxf(v[k * 4 + 3] - sub, 0.0f);
        *(float4*)(outrow + n) = o;
    }
}

extern "C" void kernel_launch(void* const* d_in, const int* in_sizes, int n_in,
                              void* d_out, int out_size, void* d_ws, size_t ws_size,
                              hipStream_t stream) {
    const float* enc  = (const float*)d_in[0];   // [B, F] f32
    const float* w    = (const float*)d_in[1];   // [N] f32
    const int*   pref = (const int*)d_in[2];     // [N] i32
    float*       out  = (float*)d_out;           // [B, N] f32
    sensory_kernel<<<B_ROWS, THREADS, 0, stream>>>(enc, w, pref, out);
}